// Round 14
// baseline (234.776 us; speedup 1.0000x reference)
//
#include <hip/hip_runtime.h>
#include <hip/hip_bf16.h>

#define B_ 32
#define N_ 512
#define D_ 512
#define E_ 8
#define P_ 96
#define KC 25
#define H_ 4
#define DK 128
#define HE 32
#define BN 16384

typedef short short8 __attribute__((ext_vector_type(8)));
typedef float f32x4 __attribute__((ext_vector_type(4)));

// ws offsets (floats). cnt zeroed + s2 computed race-free inside k_head.
#define OCNT  4096      /* 256 ints (8 counters strided by 32) */
#define OS2   4352      /* 768 */
#define OM    5120      /* 16384 */
#define OC    21504     /* 32 */
#define OA    21536     /* 524288: raw logits half-0 -> softmaxed A */
#define OAP   545824    /* 131072 */
#define OATT  676896    /* 131072 */
#define OTOK  807968    /* 131072 ints */
#define OWEFF 939040    /* 786432 bf16 = 393216 float slots */
#define OZC   1332256   /* 24576 */
#define OUP   1356832   /* 4194304: A1 partial (first 524288), then u partials */

__device__ __forceinline__ float b2f(short s) {
  unsigned u = ((unsigned)(unsigned short)s) << 16;
  return __builtin_bit_cast(float, u);
}
__device__ __forceinline__ unsigned short f2b(float f) {
  return __builtin_bit_cast(unsigned short, __float2bfloat16(f));
}

// k_head: 3 independent weight-preprocessing jobs in ONE dispatch.
__global__ __launch_bounds__(256) void k_head(const float* __restrict__ router,
        const float* __restrict__ Wq, const float* __restrict__ bq,
        const float* __restrict__ Wk, const float* __restrict__ bk,
        const float* __restrict__ Wp, const float* __restrict__ Wc,
        float* __restrict__ M, float* __restrict__ c,
        int* __restrict__ cnt, float* __restrict__ s2,
        __hip_bfloat16* __restrict__ weff) {
  __shared__ float sm[5824];
  int bid = blockIdx.x;
  int tid = threadIdx.x;
  if (bid < 64) {
    float* rs = sm;
    float* ps = sm + 512;
    float* qs = sm + 768;
    int he = bid >> 1, ch = bid & 1;
    int h = he >> 3, e = he & 7;
    for (int i = tid; i < 512; i += 256) rs[i] = router[e * D_ + i];
    __syncthreads();
    {
      int j = tid & 127, dh = tid >> 7;
      const float* wq = Wq + h * 128 + j;
      float acc = 0.f;
      for (int d = dh * 256; d < dh * 256 + 256; d += 4) {
        acc = fmaf(rs[d], wq[d * D_], acc);
        acc = fmaf(rs[d + 1], wq[(d + 1) * D_], acc);
        acc = fmaf(rs[d + 2], wq[(d + 2) * D_], acc);
        acc = fmaf(rs[d + 3], wq[(d + 3) * D_], acc);
      }
      ps[dh * 128 + j] = acc;
    }
    __syncthreads();
    if (tid < 128) qs[tid] = ps[tid] + ps[128 + tid] + bq[h * 128 + tid];
    __syncthreads();
    {
      int d0 = ch * 256 + tid;
      const float* wrow = Wk + d0 * D_ + h * 128;
      float acc = 0.f;
      for (int jj = 0; jj < 128; jj += 4) {
        float4 wv = *(const float4*)(wrow + jj);
        acc = fmaf(wv.x, qs[jj], acc);
        acc = fmaf(wv.y, qs[jj + 1], acc);
        acc = fmaf(wv.z, qs[jj + 2], acc);
        acc = fmaf(wv.w, qs[jj + 3], acc);
      }
      M[he * D_ + d0] = acc;
    }
    if (ch == 0 && tid < 64) {
      float s = qs[tid] * bk[h * 128 + tid] + qs[tid + 64] * bk[h * 128 + tid + 64];
#pragma unroll
      for (int off = 32; off; off >>= 1) s += __shfl_xor(s, off);
      if (tid == 0) c[he] = s;
    }
  } else if (bid < 192) {
    float* T = sm;
    float* wcs = sm + 5760;
    int eb = bid - 64;
    int e = eb >> 4, mc = eb & 15;
    int lo = mc * 32 - 12;
    for (int idx = tid; idx < 56 * 24; idx += 256) {
      int lp = idx / 24, p4 = (idx - lp * 24) * 4;
      int l = lo + lp;
      float4 v = {0.f, 0.f, 0.f, 0.f};
      if (l >= 0 && l < D_) v = *(const float4*)(Wp + (e * D_ + l) * P_ + p4);
      T[p4 * 60 + lp] = v.x; T[(p4 + 1) * 60 + lp] = v.y;
      T[(p4 + 2) * 60 + lp] = v.z; T[(p4 + 3) * 60 + lp] = v.w;
    }
    if (tid < 50) wcs[tid] = Wc[e * 2 * KC + tid];
    __syncthreads();
    int m = tid & 31, pg = tid >> 5;
#pragma unroll
    for (int j = 0; j < 2; ++j)
      for (int k2 = 0; k2 < 12; ++k2) {
        int p = pg * 12 + k2;
        float acc = 0.f;
#pragma unroll
        for (int k = 0; k < KC; ++k)
          acc = fmaf(wcs[j * 25 + k], T[p * 60 + m - k + 24], acc);
        weff[(((e * 2 + j) * P_ + p) << 9) + mc * 32 + m] = __float2bfloat16(acc);
      }
  } else {
    int e = bid - 192;
    if (bid == 192) cnt[tid] = 0;
    if (tid < 192) {
      int p = tid % 96, lg = tid / 96;
      float s = 0.f;
      const float* wp = Wp + e * D_ * P_ + p;
      for (int l = lg * 256; l < lg * 256 + 256; ++l) s += wp[l * P_];
      sm[lg * 96 + p] = s;
    }
    __syncthreads();
    if (tid < 96) s2[e * 96 + tid] = sm[tid] + sm[96 + tid];
  }
}

// logits: register-tiled LDS GEMM. Block = (b, 64-token tile, K-half).
__global__ __launch_bounds__(128) void k_logits(const float* __restrict__ x,
        const float* __restrict__ M, float* __restrict__ A0,
        float* __restrict__ A1) {
  __shared__ float xs[64 * 132];
  __shared__ float Ms[32 * 132];
  int dh = blockIdx.x & 1;
  int nt8 = (blockIdx.x >> 1) & 7;
  int b = blockIdx.x >> 4;
  int tid = threadIdx.x;
  const float* xb = x + (b * N_ + nt8 * 64) * D_ + dh * 256;
  const float* Mb = M + dh * 256;
  float acc[4][4] = {{0.f}};
  for (int kc = 0; kc < 2; ++kc) {
    for (int idx = tid; idx < 2048; idx += 128) {
      int r = idx >> 5, c4 = (idx & 31) * 4;
      *(float4*)(xs + r * 132 + c4) = *(const float4*)(xb + r * D_ + kc * 128 + c4);
    }
    for (int idx = tid; idx < 1024; idx += 128) {
      int r = idx >> 5, c4 = (idx & 31) * 4;
      *(float4*)(Ms + r * 132 + c4) = *(const float4*)(Mb + r * D_ + kc * 128 + c4);
    }
    __syncthreads();
    int nt = tid & 15, ht = tid >> 4;
#pragma unroll 4
    for (int d4 = 0; d4 < 128; d4 += 4) {
      float4 xv[4], mv[4];
#pragma unroll
      for (int i = 0; i < 4; ++i)
        xv[i] = *(const float4*)(xs + (nt + 16 * i) * 132 + d4);
#pragma unroll
      for (int j = 0; j < 4; ++j)
        mv[j] = *(const float4*)(Ms + (ht + 8 * j) * 132 + d4);
#pragma unroll
      for (int i = 0; i < 4; ++i)
#pragma unroll
        for (int j = 0; j < 4; ++j) {
          float s = acc[i][j];
          s = fmaf(xv[i].x, mv[j].x, s);
          s = fmaf(xv[i].y, mv[j].y, s);
          s = fmaf(xv[i].z, mv[j].z, s);
          s = fmaf(xv[i].w, mv[j].w, s);
          acc[i][j] = s;
        }
    }
    __syncthreads();
  }
  int nt = tid & 15, ht = tid >> 4;
  float* Ad = dh ? A1 : A0;
#pragma unroll
  for (int j = 0; j < 4; ++j) {
    int he = ht + 8 * j;
#pragma unroll
    for (int i = 0; i < 4; ++i)
      Ad[(b * HE + he) * N_ + nt8 * 64 + nt + 16 * i] = acc[i][j];
  }
}

// softmax over n per (b,he) row; combines d-half partials, applies scale and c[he]
__global__ __launch_bounds__(256) void k_softmax(float* __restrict__ A0,
        const float* __restrict__ A1, const float* __restrict__ c) {
  int row = blockIdx.x;
  float* p0 = A0 + row * N_;
  const float* p1 = A1 + row * N_;
  float cc = c[row & 31];
  int t = threadIdx.x;
  const float scale = 0.08838834764831845f;
  float v0 = scale * (p0[t] + p1[t] + cc);
  float v1 = scale * (p0[t + 256] + p1[t + 256] + cc);
  __shared__ float red[4], red2[4];
  float m = fmaxf(v0, v1);
#pragma unroll
  for (int off = 32; off; off >>= 1) m = fmaxf(m, __shfl_xor(m, off));
  if ((t & 63) == 0) red[t >> 6] = m;
  __syncthreads();
  m = fmaxf(fmaxf(red[0], red[1]), fmaxf(red[2], red[3]));
  float e0 = expf(v0 - m), e1 = expf(v1 - m);
  float s = e0 + e1;
#pragma unroll
  for (int off = 32; off; off >>= 1) s += __shfl_xor(s, off);
  if ((t & 63) == 0) red2[t >> 6] = s;
  __syncthreads();
  s = red2[0] + red2[1] + red2[2] + red2[3];
  float inv = 1.0f / s;
  p0[t] = e0 * inv;
  p0[t + 256] = e1 * inv;
}

// u partials over n-slices: up[b][nq][he][d] = sum_{n in slice} A[b,he,n]*x[b,n,d]
__global__ __launch_bounds__(512) void k_u2(const float* __restrict__ x,
        const float* __restrict__ A, float* __restrict__ up) {
  __shared__ float As[64 * 33];
  int nq = blockIdx.x, b = blockIdx.y;
  for (int idx = threadIdx.x; idx < 64 * 32; idx += 512) {
    int n = idx & 63, he = idx >> 6;
    As[n * 33 + he] = A[(b * HE + he) * N_ + nq * 64 + n];
  }
  __syncthreads();
  int dq = threadIdx.x & 127, hg = threadIdx.x >> 7;
  const float* xb = x + (b * N_ + nq * 64) * D_ + dq * 4;
  float acc[8][4];
#pragma unroll
  for (int j = 0; j < 8; ++j)
#pragma unroll
    for (int k = 0; k < 4; ++k) acc[j][k] = 0.f;
  for (int n = 0; n < 64; ++n) {
    float4 xv = *(const float4*)(xb + n * D_);
    const float* ar = As + n * 33 + hg * 8;
#pragma unroll
    for (int j = 0; j < 8; ++j) {
      float a = ar[j];
      acc[j][0] = fmaf(a, xv.x, acc[j][0]);
      acc[j][1] = fmaf(a, xv.y, acc[j][1]);
      acc[j][2] = fmaf(a, xv.z, acc[j][2]);
      acc[j][3] = fmaf(a, xv.w, acc[j][3]);
    }
  }
  float* o = up + (((b * 8 + nq) * HE) + hg * 8) * D_ + dq * 4;
#pragma unroll
  for (int j = 0; j < 8; ++j) {
    float4 v; v.x = acc[j][0]; v.y = acc[j][1]; v.z = acc[j][2]; v.w = acc[j][3];
    *(float4*)(o + j * D_) = v;
  }
}

// att_pre[b][e][i] = sum_d u[b,h(i)*8+e,d]*Wv[d,i] + bv[i]; u summed from partials on stage
__global__ __launch_bounds__(256) void k_attpre(const float* __restrict__ up,
        const float* __restrict__ Wv, const float* __restrict__ bv,
        float* __restrict__ ap) {
  __shared__ float us[8 * D_];
  int e = blockIdx.x & 7;
  int ic = (blockIdx.x >> 3) & 3;
  int bq = blockIdx.x >> 5;
  for (int idx = threadIdx.x; idx < 8 * 128; idx += 256) {
    int rr = idx >> 7, d4 = (idx & 127) * 4;
    const float* base = up + (((bq * 8 + rr) * 8) * HE + ic * 8 + e) * D_ + d4;
    float4 s = {0.f, 0.f, 0.f, 0.f};
#pragma unroll
    for (int nq = 0; nq < 8; ++nq) {
      float4 v = *(const float4*)(base + nq * HE * D_);
      s.x += v.x; s.y += v.y; s.z += v.z; s.w += v.w;
    }
    *(float4*)(us + rr * D_ + d4) = s;
  }
  __syncthreads();
  int i = ic * 128 + (threadIdx.x & 127);
  int bg = threadIdx.x >> 7;
  const float* usb = us + bg * 4 * D_;
  float acc[4] = {0.f, 0.f, 0.f, 0.f};
  for (int d = 0; d < D_; d += 4) {
    float w0 = Wv[(d + 0) * D_ + i];
    float w1 = Wv[(d + 1) * D_ + i];
    float w2 = Wv[(d + 2) * D_ + i];
    float w3 = Wv[(d + 3) * D_ + i];
#pragma unroll
    for (int r = 0; r < 4; ++r) {
      float4 uv = *(const float4*)(usb + r * D_ + d);
      float s = acc[r];
      s = fmaf(uv.x, w0, s); s = fmaf(uv.y, w1, s);
      s = fmaf(uv.z, w2, s); s = fmaf(uv.w, w3, s);
      acc[r] = s;
    }
  }
  float bvi = bv[i];
#pragma unroll
  for (int r = 0; r < 4; ++r)
    ap[((bq * 8 + bg * 4 + r) * E_ + e) * D_ + i] = acc[r] + bvi;
}

// att[b][e][o] = sum_i ap[b,e,i] * Wo[i,o] + bo[o]
__global__ __launch_bounds__(256) void k_att(const float* __restrict__ ap,
        const float* __restrict__ Wo, const float* __restrict__ bo,
        float* __restrict__ att) {
  __shared__ float ps[8 * D_];
  int b = blockIdx.x >> 2, oc = blockIdx.x & 3;
  for (int idx = threadIdx.x; idx < 8 * D_; idx += 256)
    ps[idx] = ap[b * E_ * D_ + idx];
  __syncthreads();
  int o = oc * 128 + (threadIdx.x & 127);
  int eg = threadIdx.x >> 7;
  const float* pe = ps + eg * 4 * D_;
  float acc[4] = {0.f, 0.f, 0.f, 0.f};
  for (int i2 = 0; i2 < D_; i2 += 4) {
    float w0 = Wo[(i2 + 0) * D_ + o];
    float w1 = Wo[(i2 + 1) * D_ + o];
    float w2 = Wo[(i2 + 2) * D_ + o];
    float w3 = Wo[(i2 + 3) * D_ + o];
#pragma unroll
    for (int r = 0; r < 4; ++r) {
      float4 pv = *(const float4*)(pe + r * D_ + i2);
      float s = acc[r];
      s = fmaf(pv.x, w0, s); s = fmaf(pv.y, w1, s);
      s = fmaf(pv.z, w2, s); s = fmaf(pv.w, w3, s);
      acc[r] = s;
    }
  }
  float boo = bo[o];
#pragma unroll
  for (int r = 0; r < 4; ++r)
    att[(b * E_ + eg * 4 + r) * D_ + o] = acc[r] + boo;
}

// routing (one wave per token) + fused zc
__global__ __launch_bounds__(256) void k_route2(const float* __restrict__ x,
        const float* __restrict__ att, const __hip_bfloat16* __restrict__ weff,
        const float* __restrict__ s2, const float* __restrict__ bc,
        const float* __restrict__ bp, int* __restrict__ cnt,
        int* __restrict__ tok, float* __restrict__ zc) {
  __shared__ float att_s[8 * D_];
  __shared__ float rn[8];
  __shared__ float red[4][520];
  __shared__ int blist[8][32];
  __shared__ int bcnt[8];
  int b = blockIdx.x >> 4, tile = blockIdx.x & 15;
  for (int idx = threadIdx.x; idx < 1024; idx += 256)
    *(float4*)(att_s + idx * 4) = *(const float4*)(att + b * E_ * D_ + idx * 4);
  if (threadIdx.x < 8) bcnt[threadIdx.x] = 0;
  __syncthreads();
  {
    int e = threadIdx.x >> 5, l = threadIdx.x & 31;
    float s = 0.f;
    for (int d0 = l; d0 < D_; d0 += 32) {
      float v = att_s[e * D_ + d0];
      s = fmaf(v, v, s);
    }
#pragma unroll
    for (int off = 16; off; off >>= 1) s += __shfl_xor(s, off);
    if (l == 0) rn[e] = 1.0f / sqrtf(s);
  }
  __syncthreads();
  int w = threadIdx.x >> 6, lane = threadIdx.x & 63;
  int e2 = lane & 7, ch = lane >> 3;
  float* rw = red[w];
  for (int i = 0; i < 8; ++i) {
    int t = b * N_ + tile * 32 + w * 8 + i;
    const float* xp = x + t * D_ + lane * 8;
    float4 xa = *(const float4*)xp;
    float4 xb4 = *(const float4*)(xp + 4);
    float p[8];
#pragma unroll
    for (int e = 0; e < 8; ++e) {
      const float* apt = att_s + e * D_ + lane * 8;
      float4 a0 = *(const float4*)apt;
      float4 a1 = *(const float4*)(apt + 4);
      float s = a0.x * xa.x;
      s = fmaf(a0.y, xa.y, s); s = fmaf(a0.z, xa.z, s); s = fmaf(a0.w, xa.w, s);
      s = fmaf(a1.x, xb4.x, s); s = fmaf(a1.y, xb4.y, s);
      s = fmaf(a1.z, xb4.z, s); s = fmaf(a1.w, xb4.w, s);
      p[e] = s;
    }
#pragma unroll
    for (int e = 0; e < 8; ++e) rw[e * 65 + lane] = p[e];
    float s = 0.f;
#pragma unroll
    for (int k = 0; k < 8; ++k) s += rw[e2 * 65 + ch * 8 + k];
    s += __shfl_xor(s, 8); s += __shfl_xor(s, 16); s += __shfl_xor(s, 32);
    float sc = s * rn[e2];
    int be = e2;
#pragma unroll
    for (int off = 1; off < 8; off <<= 1) {
      float o = __shfl_xor(sc, off);
      int oe = __shfl_xor(be, off);
      if (o > sc || (o == sc && oe < be)) { sc = o; be = oe; }
    }
    if (lane == 0) {
      int slot = atomicAdd(&bcnt[be], 1);
      blist[be][slot] = t;
    }
  }
  __syncthreads();
  {
    int e = threadIdx.x >> 5, r = threadIdx.x & 31;
    int ce = bcnt[e];
    int gs = 0;
    if (r == 0 && ce > 0) gs = atomicAdd(&cnt[e * 32], ce);
    gs = __shfl(gs, (threadIdx.x & 63) & 32);
    for (int k2 = r; k2 < ce; k2 += 32) tok[e * BN + gs + k2] = blist[e][k2];
  }
  int grp = threadIdx.x >> 4, l16 = threadIdx.x & 15;
  for (int r = 0; r < 3; ++r) {
    int P = tile * 48 + r * 16 + grp;
    int ez = P / 96, p = P - ez * 96;
    const short* wrow = (const short*)weff + (((ez * 2 + 1) * P_ + p) << 9);
    const float* arow = att_s + ez * D_;
    float acc = 0.f;
#pragma unroll
    for (int seg = 0; seg < 4; ++seg) {
      int d = seg * 128 + l16 * 8;
      short8 w8 = *(const short8*)(wrow + d);
      const float* a8 = arow + d;
      acc = fmaf(a8[0], b2f(w8[0]), acc); acc = fmaf(a8[1], b2f(w8[1]), acc);
      acc = fmaf(a8[2], b2f(w8[2]), acc); acc = fmaf(a8[3], b2f(w8[3]), acc);
      acc = fmaf(a8[4], b2f(w8[4]), acc); acc = fmaf(a8[5], b2f(w8[5]), acc);
      acc = fmaf(a8[6], b2f(w8[6]), acc); acc = fmaf(a8[7], b2f(w8[7]), acc);
    }
    acc += __shfl_xor(acc, 1); acc += __shfl_xor(acc, 2);
    acc += __shfl_xor(acc, 4); acc += __shfl_xor(acc, 8);
    if (l16 == 0)
      zc[(b * E_ + ez) * P_ + p] = acc + bc[ez] * s2[ez * 96 + p] + bp[ez * 96 + p];
  }
}

// grouped final GEMM: exactly-sized segmented grid, 256 threads (4 waves),
// 32 tokens x 96 cols per block.
__global__ __launch_bounds__(256) void k_final(const float* __restrict__ x,
        const __hip_bfloat16* __restrict__ weff, const float* __restrict__ zc,
        const int* __restrict__ cnt, const int* __restrict__ tok,
        float* __restrict__ out) {
  __shared__ __align__(16) unsigned short xsb[32 * 520];
  __shared__ int toks[32];
  int g = blockIdx.x;
  int cl_e[E_], bs[E_ + 1];
  bs[0] = 0;
#pragma unroll
  for (int e = 0; e < E_; ++e) {
    cl_e[e] = cnt[e * 32];
    bs[e + 1] = bs[e] + ((cl_e[e] + 31) >> 5);
  }
  if (g >= bs[E_]) return;
  int e = 0;
#pragma unroll
  for (int k = 1; k < E_; ++k) if (g >= bs[k]) e = k;
  int base = (g - bs[e]) * 32;
  int cnt_e = cl_e[e];
  int cl = cnt_e - base; if (cl > 32) cl = 32;
  int tid = threadIdx.x;
  if (tid < 32) toks[tid] = (tid < cl) ? tok[e * BN + base + tid] : tok[e * BN + base];
  __syncthreads();
  for (int idx = tid; idx < 32 * 128; idx += 256) {
    int r = idx >> 7, c4 = (idx & 127) * 4;
    float4 v = *(const float4*)(x + toks[r] * D_ + c4);
    ushort4 u4;
    u4.x = f2b(v.x); u4.y = f2b(v.y); u4.z = f2b(v.z); u4.w = f2b(v.w);
    *(ushort4*)(xsb + r * 520 + c4) = u4;
  }
  __syncthreads();
  int wave = tid >> 6, lane = tid & 63;
  int mw = wave & 1, nw = wave >> 1;
  int m16 = lane & 15, quad = lane >> 4;
  const short* w0 = (const short*)(weff + (e * 2 + 0) * P_ * D_);
  f32x4 acc[3];
#pragma unroll
  for (int nt = 0; nt < 3; ++nt) acc[nt] = (f32x4){0.f, 0.f, 0.f, 0.f};
  const short* arow = (const short*)xsb + (mw * 16 + m16) * 520 + quad * 8;
  const short* brow = w0 + (nw * 48 + m16) * D_ + quad * 8;
  for (int kt = 0; kt < 16; ++kt) {
    int koff = kt * 32;
    short8 a = *(const short8*)(arow + koff);
#pragma unroll
    for (int nt = 0; nt < 3; ++nt) {
      short8 bf = *(const short8*)(brow + nt * 16 * D_ + koff);
      acc[nt] = __builtin_amdgcn_mfma_f32_16x16x32_bf16(a, bf, acc[nt], 0, 0, 0);
    }
  }
#pragma unroll
  for (int nt = 0; nt < 3; ++nt)
#pragma unroll
    for (int rr = 0; rr < 4; ++rr) {
      int row = mw * 16 + quad * 4 + rr;
      if (row < cl) {
        int tg = toks[row];
        int bb = tg >> 9;
        int p = nw * 48 + nt * 16 + m16;
        out[tg * P_ + p] = acc[nt][rr] + zc[(bb * E_ + e) * P_ + p];
      }
    }
}

extern "C" void kernel_launch(void* const* d_in, const int* in_sizes, int n_in,
                              void* d_out, int out_size, void* d_ws, size_t ws_size,
                              hipStream_t stream) {
  const float* x      = (const float*)d_in[0];
  const float* router = (const float*)d_in[1];
  const float* Wq     = (const float*)d_in[2];
  const float* bq     = (const float*)d_in[3];
  const float* Wk     = (const float*)d_in[4];
  const float* bk     = (const float*)d_in[5];
  const float* Wv     = (const float*)d_in[6];
  const float* bv     = (const float*)d_in[7];
  const float* Wo     = (const float*)d_in[8];
  const float* bo     = (const float*)d_in[9];
  const float* Wc     = (const float*)d_in[10];
  const float* bc     = (const float*)d_in[11];
  const float* Wp     = (const float*)d_in[12];
  const float* bp     = (const float*)d_in[13];
  float* out = (float*)d_out;
  float* w = (float*)d_ws;

  int*   cnt  = (int*)(w + OCNT);
  float* s2   = w + OS2;
  float* M    = w + OM;
  float* c    = w + OC;
  float* A0   = w + OA;
  float* A1   = w + OUP;   // aliases up region; consumed by k_softmax before k_u2
  float* ap   = w + OAP;
  float* att  = w + OATT;
  int*   tok  = (int*)(w + OTOK);
  __hip_bfloat16* weff = (__hip_bfloat16*)(w + OWEFF);
  float* zc   = w + OZC;
  float* up   = w + OUP;

  k_head<<<200, 256, 0, stream>>>(router, Wq, bq, Wk, bk, Wp, Wc, M, c, cnt, s2, weff);
  k_logits<<<512, 128, 0, stream>>>(x, M, A0, A1);
  k_softmax<<<1024, 256, 0, stream>>>(A0, A1, c);
  k_u2<<<dim3(8, 32), 512, 0, stream>>>(x, A0, up);
  k_attpre<<<128, 256, 0, stream>>>(up, Wv, bv, ap);
  k_att<<<128, 256, 0, stream>>>(ap, Wo, bo, att);
  k_route2<<<512, 256, 0, stream>>>(x, att, weff, s2, bc, bp, cnt, tok, zc);
  k_final<<<520, 256, 0, stream>>>(x, weff, zc, cnt, tok, out);
}

// Round 15
// 226.667 us; speedup vs baseline: 1.0358x; 1.0358x over previous
//
#include <hip/hip_runtime.h>
#include <hip/hip_bf16.h>

#define B_ 32
#define N_ 512
#define D_ 512
#define E_ 8
#define P_ 96
#define KC 25
#define H_ 4
#define DK 128
#define HE 32
#define BN 16384

typedef short short8 __attribute__((ext_vector_type(8)));
typedef float f32x4 __attribute__((ext_vector_type(4)));

// ws offsets (floats). cnt zeroed + s2 computed race-free inside k_head.
#define OCNT  4096      /* 256 ints (8 counters strided by 32) */
#define OS2   4352      /* 768 */
#define OM    5120      /* 16384 */
#define OC    21504     /* 32 */
#define OA    21536     /* 524288: raw logits half-0 -> softmaxed A */
#define OATT  676896    /* 131072 */
#define OTOK  807968    /* 131072 ints */
#define OWEFF 939040    /* 786432 bf16 = 393216 float slots */
#define OZC   1332256   /* 24576 */
#define OUP   1356832   /* 4194304: A1 partial (first 524288), then u partials */

__device__ __forceinline__ float b2f(short s) {
  unsigned u = ((unsigned)(unsigned short)s) << 16;
  return __builtin_bit_cast(float, u);
}
__device__ __forceinline__ unsigned short f2b(float f) {
  return __builtin_bit_cast(unsigned short, __float2bfloat16(f));
}

// k_head: 3 independent weight-preprocessing jobs in ONE dispatch.
__global__ __launch_bounds__(256) void k_head(const float* __restrict__ router,
        const float* __restrict__ Wq, const float* __restrict__ bq,
        const float* __restrict__ Wk, const float* __restrict__ bk,
        const float* __restrict__ Wp, const float* __restrict__ Wc,
        float* __restrict__ M, float* __restrict__ c,
        int* __restrict__ cnt, float* __restrict__ s2,
        __hip_bfloat16* __restrict__ weff) {
  __shared__ float sm[5824];
  int bid = blockIdx.x;
  int tid = threadIdx.x;
  if (bid < 64) {
    float* rs = sm;
    float* ps = sm + 512;
    float* qs = sm + 768;
    int he = bid >> 1, ch = bid & 1;
    int h = he >> 3, e = he & 7;
    for (int i = tid; i < 512; i += 256) rs[i] = router[e * D_ + i];
    __syncthreads();
    {
      int j = tid & 127, dh = tid >> 7;
      const float* wq = Wq + h * 128 + j;
      float acc = 0.f;
      for (int d = dh * 256; d < dh * 256 + 256; d += 4) {
        acc = fmaf(rs[d], wq[d * D_], acc);
        acc = fmaf(rs[d + 1], wq[(d + 1) * D_], acc);
        acc = fmaf(rs[d + 2], wq[(d + 2) * D_], acc);
        acc = fmaf(rs[d + 3], wq[(d + 3) * D_], acc);
      }
      ps[dh * 128 + j] = acc;
    }
    __syncthreads();
    if (tid < 128) qs[tid] = ps[tid] + ps[128 + tid] + bq[h * 128 + tid];
    __syncthreads();
    {
      int d0 = ch * 256 + tid;
      const float* wrow = Wk + d0 * D_ + h * 128;
      float acc = 0.f;
      for (int jj = 0; jj < 128; jj += 4) {
        float4 wv = *(const float4*)(wrow + jj);
        acc = fmaf(wv.x, qs[jj], acc);
        acc = fmaf(wv.y, qs[jj + 1], acc);
        acc = fmaf(wv.z, qs[jj + 2], acc);
        acc = fmaf(wv.w, qs[jj + 3], acc);
      }
      M[he * D_ + d0] = acc;
    }
    if (ch == 0 && tid < 64) {
      float s = qs[tid] * bk[h * 128 + tid] + qs[tid + 64] * bk[h * 128 + tid + 64];
#pragma unroll
      for (int off = 32; off; off >>= 1) s += __shfl_xor(s, off);
      if (tid == 0) c[he] = s;
    }
  } else if (bid < 192) {
    float* T = sm;
    float* wcs = sm + 5760;
    int eb = bid - 64;
    int e = eb >> 4, mc = eb & 15;
    int lo = mc * 32 - 12;
    for (int idx = tid; idx < 56 * 24; idx += 256) {
      int lp = idx / 24, p4 = (idx - lp * 24) * 4;
      int l = lo + lp;
      float4 v = {0.f, 0.f, 0.f, 0.f};
      if (l >= 0 && l < D_) v = *(const float4*)(Wp + (e * D_ + l) * P_ + p4);
      T[p4 * 60 + lp] = v.x; T[(p4 + 1) * 60 + lp] = v.y;
      T[(p4 + 2) * 60 + lp] = v.z; T[(p4 + 3) * 60 + lp] = v.w;
    }
    if (tid < 50) wcs[tid] = Wc[e * 2 * KC + tid];
    __syncthreads();
    int m = tid & 31, pg = tid >> 5;
#pragma unroll
    for (int j = 0; j < 2; ++j)
      for (int k2 = 0; k2 < 12; ++k2) {
        int p = pg * 12 + k2;
        float acc = 0.f;
#pragma unroll
        for (int k = 0; k < KC; ++k)
          acc = fmaf(wcs[j * 25 + k], T[p * 60 + m - k + 24], acc);
        weff[(((e * 2 + j) * P_ + p) << 9) + mc * 32 + m] = __float2bfloat16(acc);
      }
  } else {
    int e = bid - 192;
    if (bid == 192) cnt[tid] = 0;
    if (tid < 192) {
      int p = tid % 96, lg = tid / 96;
      float s = 0.f;
      const float* wp = Wp + e * D_ * P_ + p;
      for (int l = lg * 256; l < lg * 256 + 256; ++l) s += wp[l * P_];
      sm[lg * 96 + p] = s;
    }
    __syncthreads();
    if (tid < 96) s2[e * 96 + tid] = sm[tid] + sm[96 + tid];
  }
}

// logits: register-tiled LDS GEMM. Block = (b, 64-token tile, K-half).
__global__ __launch_bounds__(128) void k_logits(const float* __restrict__ x,
        const float* __restrict__ M, float* __restrict__ A0,
        float* __restrict__ A1) {
  __shared__ float xs[64 * 132];
  __shared__ float Ms[32 * 132];
  int dh = blockIdx.x & 1;
  int nt8 = (blockIdx.x >> 1) & 7;
  int b = blockIdx.x >> 4;
  int tid = threadIdx.x;
  const float* xb = x + (b * N_ + nt8 * 64) * D_ + dh * 256;
  const float* Mb = M + dh * 256;
  float acc[4][4] = {{0.f}};
  for (int kc = 0; kc < 2; ++kc) {
    for (int idx = tid; idx < 2048; idx += 128) {
      int r = idx >> 5, c4 = (idx & 31) * 4;
      *(float4*)(xs + r * 132 + c4) = *(const float4*)(xb + r * D_ + kc * 128 + c4);
    }
    for (int idx = tid; idx < 1024; idx += 128) {
      int r = idx >> 5, c4 = (idx & 31) * 4;
      *(float4*)(Ms + r * 132 + c4) = *(const float4*)(Mb + r * D_ + kc * 128 + c4);
    }
    __syncthreads();
    int nt = tid & 15, ht = tid >> 4;
#pragma unroll 4
    for (int d4 = 0; d4 < 128; d4 += 4) {
      float4 xv[4], mv[4];
#pragma unroll
      for (int i = 0; i < 4; ++i)
        xv[i] = *(const float4*)(xs + (nt + 16 * i) * 132 + d4);
#pragma unroll
      for (int j = 0; j < 4; ++j)
        mv[j] = *(const float4*)(Ms + (ht + 8 * j) * 132 + d4);
#pragma unroll
      for (int i = 0; i < 4; ++i)
#pragma unroll
        for (int j = 0; j < 4; ++j) {
          float s = acc[i][j];
          s = fmaf(xv[i].x, mv[j].x, s);
          s = fmaf(xv[i].y, mv[j].y, s);
          s = fmaf(xv[i].z, mv[j].z, s);
          s = fmaf(xv[i].w, mv[j].w, s);
          acc[i][j] = s;
        }
    }
    __syncthreads();
  }
  int nt = tid & 15, ht = tid >> 4;
  float* Ad = dh ? A1 : A0;
#pragma unroll
  for (int j = 0; j < 4; ++j) {
    int he = ht + 8 * j;
#pragma unroll
    for (int i = 0; i < 4; ++i)
      Ad[(b * HE + he) * N_ + nt8 * 64 + nt + 16 * i] = acc[i][j];
  }
}

// softmax over n per (b,he) row; combines d-half partials, applies scale and c[he]
__global__ __launch_bounds__(256) void k_softmax(float* __restrict__ A0,
        const float* __restrict__ A1, const float* __restrict__ c) {
  int row = blockIdx.x;
  float* p0 = A0 + row * N_;
  const float* p1 = A1 + row * N_;
  float cc = c[row & 31];
  int t = threadIdx.x;
  const float scale = 0.08838834764831845f;
  float v0 = scale * (p0[t] + p1[t] + cc);
  float v1 = scale * (p0[t + 256] + p1[t + 256] + cc);
  __shared__ float red[4], red2[4];
  float m = fmaxf(v0, v1);
#pragma unroll
  for (int off = 32; off; off >>= 1) m = fmaxf(m, __shfl_xor(m, off));
  if ((t & 63) == 0) red[t >> 6] = m;
  __syncthreads();
  m = fmaxf(fmaxf(red[0], red[1]), fmaxf(red[2], red[3]));
  float e0 = expf(v0 - m), e1 = expf(v1 - m);
  float s = e0 + e1;
#pragma unroll
  for (int off = 32; off; off >>= 1) s += __shfl_xor(s, off);
  if ((t & 63) == 0) red2[t >> 6] = s;
  __syncthreads();
  s = red2[0] + red2[1] + red2[2] + red2[3];
  float inv = 1.0f / s;
  p0[t] = e0 * inv;
  p0[t + 256] = e1 * inv;
}

// u partials over n-slices: up[b][nq][he][d] = sum_{n in slice} A[b,he,n]*x[b,n,d]
__global__ __launch_bounds__(512) void k_u2(const float* __restrict__ x,
        const float* __restrict__ A, float* __restrict__ up) {
  __shared__ float As[64 * 33];
  int nq = blockIdx.x, b = blockIdx.y;
  for (int idx = threadIdx.x; idx < 64 * 32; idx += 512) {
    int n = idx & 63, he = idx >> 6;
    As[n * 33 + he] = A[(b * HE + he) * N_ + nq * 64 + n];
  }
  __syncthreads();
  int dq = threadIdx.x & 127, hg = threadIdx.x >> 7;
  const float* xb = x + (b * N_ + nq * 64) * D_ + dq * 4;
  float acc[8][4];
#pragma unroll
  for (int j = 0; j < 8; ++j)
#pragma unroll
    for (int k = 0; k < 4; ++k) acc[j][k] = 0.f;
  for (int n = 0; n < 64; ++n) {
    float4 xv = *(const float4*)(xb + n * D_);
    const float* ar = As + n * 33 + hg * 8;
#pragma unroll
    for (int j = 0; j < 8; ++j) {
      float a = ar[j];
      acc[j][0] = fmaf(a, xv.x, acc[j][0]);
      acc[j][1] = fmaf(a, xv.y, acc[j][1]);
      acc[j][2] = fmaf(a, xv.z, acc[j][2]);
      acc[j][3] = fmaf(a, xv.w, acc[j][3]);
    }
  }
  float* o = up + (((b * 8 + nq) * HE) + hg * 8) * D_ + dq * 4;
#pragma unroll
  for (int j = 0; j < 8; ++j) {
    float4 v; v.x = acc[j][0]; v.y = acc[j][1]; v.z = acc[j][2]; v.w = acc[j][3];
    *(float4*)(o + j * D_) = v;
  }
}

// fused V+O projection v3, job = (b,e). 256 blocks x 512 thr.
// Each GEMV phase: thread (c=tid>>7, j=tid&127) owns 4 consecutive outputs
// x d-chunk c of 128 — float4 coalesced weight loads, LDS-broadcast operand,
// 4 partials combined through LDS.
__global__ __launch_bounds__(512) void k_vo3(const float* __restrict__ up,
        const float* __restrict__ Wv, const float* __restrict__ bv,
        const float* __restrict__ Wo, const float* __restrict__ bo,
        float* __restrict__ att) {
  __shared__ float us[4 * 512];
  __shared__ float part[4 * 512];
  __shared__ float ap_s[512];
  int b = blockIdx.x >> 3, e = blockIdx.x & 7;
  int tid = threadIdx.x;
  // stage u rows {h*8+e}, nq-summed
  for (int idx = tid; idx < 4 * 128; idx += 512) {
    int h = idx >> 7, d4 = (idx & 127) * 4;
    const float* base = up + ((b * 8) * HE + h * 8 + e) * D_ + d4;
    float4 s = {0.f, 0.f, 0.f, 0.f};
#pragma unroll
    for (int nq = 0; nq < 8; ++nq) {
      float4 v = *(const float4*)(base + nq * HE * D_);
      s.x += v.x; s.y += v.y; s.z += v.z; s.w += v.w;
    }
    *(float4*)(us + h * 512 + d4) = s;
  }
  __syncthreads();
  {
    int cch = tid >> 7, j = tid & 127;
    int i0 = j * 4;
    int h = j >> 5;                 // i0>>7 — uniform per thread
    const float* ur = us + h * 512;
    const float* wv = Wv + i0;
    float4 acc = {0.f, 0.f, 0.f, 0.f};
    int d0 = cch * 128;
#pragma unroll 4
    for (int d = d0; d < d0 + 128; ++d) {
      float4 wq = *(const float4*)(wv + d * D_);
      float a = ur[d];
      acc.x = fmaf(a, wq.x, acc.x);
      acc.y = fmaf(a, wq.y, acc.y);
      acc.z = fmaf(a, wq.z, acc.z);
      acc.w = fmaf(a, wq.w, acc.w);
    }
    *(float4*)(part + cch * 512 + i0) = acc;
  }
  __syncthreads();
  ap_s[tid] = part[tid] + part[512 + tid] + part[1024 + tid] + part[1536 + tid]
              + bv[tid];
  __syncthreads();
  {
    int cch = tid >> 7, j = tid & 127;
    int o0 = j * 4;
    const float* wo = Wo + o0;
    float4 acc = {0.f, 0.f, 0.f, 0.f};
    int i0 = cch * 128;
#pragma unroll 4
    for (int i = i0; i < i0 + 128; ++i) {
      float4 wq = *(const float4*)(wo + i * D_);
      float a = ap_s[i];
      acc.x = fmaf(a, wq.x, acc.x);
      acc.y = fmaf(a, wq.y, acc.y);
      acc.z = fmaf(a, wq.z, acc.z);
      acc.w = fmaf(a, wq.w, acc.w);
    }
    *(float4*)(part + cch * 512 + o0) = acc;
  }
  __syncthreads();
  att[(b * E_ + e) * D_ + tid] = part[tid] + part[512 + tid] + part[1024 + tid]
                                 + part[1536 + tid] + bo[tid];
}

// routing (one wave per token) + fused zc
__global__ __launch_bounds__(256) void k_route2(const float* __restrict__ x,
        const float* __restrict__ att, const __hip_bfloat16* __restrict__ weff,
        const float* __restrict__ s2, const float* __restrict__ bc,
        const float* __restrict__ bp, int* __restrict__ cnt,
        int* __restrict__ tok, float* __restrict__ zc) {
  __shared__ float att_s[8 * D_];
  __shared__ float rn[8];
  __shared__ float red[4][520];
  __shared__ int blist[8][32];
  __shared__ int bcnt[8];
  int b = blockIdx.x >> 4, tile = blockIdx.x & 15;
  for (int idx = threadIdx.x; idx < 1024; idx += 256)
    *(float4*)(att_s + idx * 4) = *(const float4*)(att + b * E_ * D_ + idx * 4);
  if (threadIdx.x < 8) bcnt[threadIdx.x] = 0;
  __syncthreads();
  {
    int e = threadIdx.x >> 5, l = threadIdx.x & 31;
    float s = 0.f;
    for (int d0 = l; d0 < D_; d0 += 32) {
      float v = att_s[e * D_ + d0];
      s = fmaf(v, v, s);
    }
#pragma unroll
    for (int off = 16; off; off >>= 1) s += __shfl_xor(s, off);
    if (l == 0) rn[e] = 1.0f / sqrtf(s);
  }
  __syncthreads();
  int w = threadIdx.x >> 6, lane = threadIdx.x & 63;
  int e2 = lane & 7, ch = lane >> 3;
  float* rw = red[w];
  for (int i = 0; i < 8; ++i) {
    int t = b * N_ + tile * 32 + w * 8 + i;
    const float* xp = x + t * D_ + lane * 8;
    float4 xa = *(const float4*)xp;
    float4 xb4 = *(const float4*)(xp + 4);
    float p[8];
#pragma unroll
    for (int e = 0; e < 8; ++e) {
      const float* apt = att_s + e * D_ + lane * 8;
      float4 a0 = *(const float4*)apt;
      float4 a1 = *(const float4*)(apt + 4);
      float s = a0.x * xa.x;
      s = fmaf(a0.y, xa.y, s); s = fmaf(a0.z, xa.z, s); s = fmaf(a0.w, xa.w, s);
      s = fmaf(a1.x, xb4.x, s); s = fmaf(a1.y, xb4.y, s);
      s = fmaf(a1.z, xb4.z, s); s = fmaf(a1.w, xb4.w, s);
      p[e] = s;
    }
#pragma unroll
    for (int e = 0; e < 8; ++e) rw[e * 65 + lane] = p[e];
    float s = 0.f;
#pragma unroll
    for (int k = 0; k < 8; ++k) s += rw[e2 * 65 + ch * 8 + k];
    s += __shfl_xor(s, 8); s += __shfl_xor(s, 16); s += __shfl_xor(s, 32);
    float sc = s * rn[e2];
    int be = e2;
#pragma unroll
    for (int off = 1; off < 8; off <<= 1) {
      float o = __shfl_xor(sc, off);
      int oe = __shfl_xor(be, off);
      if (o > sc || (o == sc && oe < be)) { sc = o; be = oe; }
    }
    if (lane == 0) {
      int slot = atomicAdd(&bcnt[be], 1);
      blist[be][slot] = t;
    }
  }
  __syncthreads();
  {
    int e = threadIdx.x >> 5, r = threadIdx.x & 31;
    int ce = bcnt[e];
    int gs = 0;
    if (r == 0 && ce > 0) gs = atomicAdd(&cnt[e * 32], ce);
    gs = __shfl(gs, (threadIdx.x & 63) & 32);
    for (int k2 = r; k2 < ce; k2 += 32) tok[e * BN + gs + k2] = blist[e][k2];
  }
  int grp = threadIdx.x >> 4, l16 = threadIdx.x & 15;
  for (int r = 0; r < 3; ++r) {
    int P = tile * 48 + r * 16 + grp;
    int ez = P / 96, p = P - ez * 96;
    const short* wrow = (const short*)weff + (((ez * 2 + 1) * P_ + p) << 9);
    const float* arow = att_s + ez * D_;
    float acc = 0.f;
#pragma unroll
    for (int seg = 0; seg < 4; ++seg) {
      int d = seg * 128 + l16 * 8;
      short8 w8 = *(const short8*)(wrow + d);
      const float* a8 = arow + d;
      acc = fmaf(a8[0], b2f(w8[0]), acc); acc = fmaf(a8[1], b2f(w8[1]), acc);
      acc = fmaf(a8[2], b2f(w8[2]), acc); acc = fmaf(a8[3], b2f(w8[3]), acc);
      acc = fmaf(a8[4], b2f(w8[4]), acc); acc = fmaf(a8[5], b2f(w8[5]), acc);
      acc = fmaf(a8[6], b2f(w8[6]), acc); acc = fmaf(a8[7], b2f(w8[7]), acc);
    }
    acc += __shfl_xor(acc, 1); acc += __shfl_xor(acc, 2);
    acc += __shfl_xor(acc, 4); acc += __shfl_xor(acc, 8);
    if (l16 == 0)
      zc[(b * E_ + ez) * P_ + p] = acc + bc[ez] * s2[ez * 96 + p] + bp[ez * 96 + p];
  }
}

// grouped final GEMM: exactly-sized segmented grid, 256 threads (4 waves),
// 32 tokens x 96 cols per block.
__global__ __launch_bounds__(256) void k_final(const float* __restrict__ x,
        const __hip_bfloat16* __restrict__ weff, const float* __restrict__ zc,
        const int* __restrict__ cnt, const int* __restrict__ tok,
        float* __restrict__ out) {
  __shared__ __align__(16) unsigned short xsb[32 * 520];
  __shared__ int toks[32];
  int g = blockIdx.x;
  int cl_e[E_], bs[E_ + 1];
  bs[0] = 0;
#pragma unroll
  for (int e = 0; e < E_; ++e) {
    cl_e[e] = cnt[e * 32];
    bs[e + 1] = bs[e] + ((cl_e[e] + 31) >> 5);
  }
  if (g >= bs[E_]) return;
  int e = 0;
#pragma unroll
  for (int k = 1; k < E_; ++k) if (g >= bs[k]) e = k;
  int base = (g - bs[e]) * 32;
  int cnt_e = cl_e[e];
  int cl = cnt_e - base; if (cl > 32) cl = 32;
  int tid = threadIdx.x;
  if (tid < 32) toks[tid] = (tid < cl) ? tok[e * BN + base + tid] : tok[e * BN + base];
  __syncthreads();
  for (int idx = tid; idx < 32 * 128; idx += 256) {
    int r = idx >> 7, c4 = (idx & 127) * 4;
    float4 v = *(const float4*)(x + toks[r] * D_ + c4);
    ushort4 u4;
    u4.x = f2b(v.x); u4.y = f2b(v.y); u4.z = f2b(v.z); u4.w = f2b(v.w);
    *(ushort4*)(xsb + r * 520 + c4) = u4;
  }
  __syncthreads();
  int wave = tid >> 6, lane = tid & 63;
  int mw = wave & 1, nw = wave >> 1;
  int m16 = lane & 15, quad = lane >> 4;
  const short* w0 = (const short*)(weff + (e * 2 + 0) * P_ * D_);
  f32x4 acc[3];
#pragma unroll
  for (int nt = 0; nt < 3; ++nt) acc[nt] = (f32x4){0.f, 0.f, 0.f, 0.f};
  const short* arow = (const short*)xsb + (mw * 16 + m16) * 520 + quad * 8;
  const short* brow = w0 + (nw * 48 + m16) * D_ + quad * 8;
  for (int kt = 0; kt < 16; ++kt) {
    int koff = kt * 32;
    short8 a = *(const short8*)(arow + koff);
#pragma unroll
    for (int nt = 0; nt < 3; ++nt) {
      short8 bf = *(const short8*)(brow + nt * 16 * D_ + koff);
      acc[nt] = __builtin_amdgcn_mfma_f32_16x16x32_bf16(a, bf, acc[nt], 0, 0, 0);
    }
  }
#pragma unroll
  for (int nt = 0; nt < 3; ++nt)
#pragma unroll
    for (int rr = 0; rr < 4; ++rr) {
      int row = mw * 16 + quad * 4 + rr;
      if (row < cl) {
        int tg = toks[row];
        int bb = tg >> 9;
        int p = nw * 48 + nt * 16 + m16;
        out[tg * P_ + p] = acc[nt][rr] + zc[(bb * E_ + e) * P_ + p];
      }
    }
}

extern "C" void kernel_launch(void* const* d_in, const int* in_sizes, int n_in,
                              void* d_out, int out_size, void* d_ws, size_t ws_size,
                              hipStream_t stream) {
  const float* x      = (const float*)d_in[0];
  const float* router = (const float*)d_in[1];
  const float* Wq     = (const float*)d_in[2];
  const float* bq     = (const float*)d_in[3];
  const float* Wk     = (const float*)d_in[4];
  const float* bk     = (const float*)d_in[5];
  const float* Wv     = (const float*)d_in[6];
  const float* bv     = (const float*)d_in[7];
  const float* Wo     = (const float*)d_in[8];
  const float* bo     = (const float*)d_in[9];
  const float* Wc     = (const float*)d_in[10];
  const float* bc     = (const float*)d_in[11];
  const float* Wp     = (const float*)d_in[12];
  const float* bp     = (const float*)d_in[13];
  float* out = (float*)d_out;
  float* w = (float*)d_ws;

  int*   cnt  = (int*)(w + OCNT);
  float* s2   = w + OS2;
  float* M    = w + OM;
  float* c    = w + OC;
  float* A0   = w + OA;
  float* A1   = w + OUP;   // aliases up region; consumed by k_softmax before k_u2
  float* att  = w + OATT;
  int*   tok  = (int*)(w + OTOK);
  __hip_bfloat16* weff = (__hip_bfloat16*)(w + OWEFF);
  float* zc   = w + OZC;
  float* up   = w + OUP;

  k_head<<<200, 256, 0, stream>>>(router, Wq, bq, Wk, bk, Wp, Wc, M, c, cnt, s2, weff);
  k_logits<<<512, 128, 0, stream>>>(x, M, A0, A1);
  k_softmax<<<1024, 256, 0, stream>>>(A0, A1, c);
  k_u2<<<dim3(8, 32), 512, 0, stream>>>(x, A0, up);
  k_vo3<<<256, 512, 0, stream>>>(up, Wv, bv, Wo, bo, att);
  k_route2<<<512, 256, 0, stream>>>(x, att, weff, s2, bc, bp, cnt, tok, zc);
  k_final<<<520, 256, 0, stream>>>(x, weff, zc, cnt, tok, out);
}

// Round 16
// 222.421 us; speedup vs baseline: 1.0555x; 1.0191x over previous
//
#include <hip/hip_runtime.h>
#include <hip/hip_bf16.h>

#define B_ 32
#define N_ 512
#define D_ 512
#define E_ 8
#define P_ 96
#define KC 25
#define H_ 4
#define DK 128
#define HE 32
#define BN 16384

typedef short short8 __attribute__((ext_vector_type(8)));
typedef float f32x4 __attribute__((ext_vector_type(4)));

// ws offsets (floats). cnt zeroed + s2 computed race-free inside k_head.
#define OCNT  4096      /* 256 ints (8 counters strided by 32) */
#define OS2   4352      /* 768 */
#define OM    5120      /* 16384 */
#define OC    21504     /* 32 */
#define OA    21536     /* 524288: raw logits half-0 */
#define OATT  676896    /* 131072 */
#define OTOK  807968    /* 131072 ints */
#define OWEFF 939040    /* 786432 bf16 = 393216 float slots */
#define OZC   1332256   /* 24576 */
#define OUP   1356832   /* 4194304: u partials */
#define OA1   5551136   /* 524288: raw logits half-1 (own buffer — up is live in k_u3) */

__device__ __forceinline__ float b2f(short s) {
  unsigned u = ((unsigned)(unsigned short)s) << 16;
  return __builtin_bit_cast(float, u);
}
__device__ __forceinline__ unsigned short f2b(float f) {
  return __builtin_bit_cast(unsigned short, __float2bfloat16(f));
}

// k_head: 3 independent weight-preprocessing jobs in ONE dispatch.
__global__ __launch_bounds__(256) void k_head(const float* __restrict__ router,
        const float* __restrict__ Wq, const float* __restrict__ bq,
        const float* __restrict__ Wk, const float* __restrict__ bk,
        const float* __restrict__ Wp, const float* __restrict__ Wc,
        float* __restrict__ M, float* __restrict__ c,
        int* __restrict__ cnt, float* __restrict__ s2,
        __hip_bfloat16* __restrict__ weff) {
  __shared__ float sm[5824];
  int bid = blockIdx.x;
  int tid = threadIdx.x;
  if (bid < 64) {
    float* rs = sm;
    float* ps = sm + 512;
    float* qs = sm + 768;
    int he = bid >> 1, ch = bid & 1;
    int h = he >> 3, e = he & 7;
    for (int i = tid; i < 512; i += 256) rs[i] = router[e * D_ + i];
    __syncthreads();
    {
      int j = tid & 127, dh = tid >> 7;
      const float* wq = Wq + h * 128 + j;
      float acc = 0.f;
      for (int d = dh * 256; d < dh * 256 + 256; d += 4) {
        acc = fmaf(rs[d], wq[d * D_], acc);
        acc = fmaf(rs[d + 1], wq[(d + 1) * D_], acc);
        acc = fmaf(rs[d + 2], wq[(d + 2) * D_], acc);
        acc = fmaf(rs[d + 3], wq[(d + 3) * D_], acc);
      }
      ps[dh * 128 + j] = acc;
    }
    __syncthreads();
    if (tid < 128) qs[tid] = ps[tid] + ps[128 + tid] + bq[h * 128 + tid];
    __syncthreads();
    {
      int d0 = ch * 256 + tid;
      const float* wrow = Wk + d0 * D_ + h * 128;
      float acc = 0.f;
      for (int jj = 0; jj < 128; jj += 4) {
        float4 wv = *(const float4*)(wrow + jj);
        acc = fmaf(wv.x, qs[jj], acc);
        acc = fmaf(wv.y, qs[jj + 1], acc);
        acc = fmaf(wv.z, qs[jj + 2], acc);
        acc = fmaf(wv.w, qs[jj + 3], acc);
      }
      M[he * D_ + d0] = acc;
    }
    if (ch == 0 && tid < 64) {
      float s = qs[tid] * bk[h * 128 + tid] + qs[tid + 64] * bk[h * 128 + tid + 64];
#pragma unroll
      for (int off = 32; off; off >>= 1) s += __shfl_xor(s, off);
      if (tid == 0) c[he] = s;
    }
  } else if (bid < 192) {
    float* T = sm;
    float* wcs = sm + 5760;
    int eb = bid - 64;
    int e = eb >> 4, mc = eb & 15;
    int lo = mc * 32 - 12;
    for (int idx = tid; idx < 56 * 24; idx += 256) {
      int lp = idx / 24, p4 = (idx - lp * 24) * 4;
      int l = lo + lp;
      float4 v = {0.f, 0.f, 0.f, 0.f};
      if (l >= 0 && l < D_) v = *(const float4*)(Wp + (e * D_ + l) * P_ + p4);
      T[p4 * 60 + lp] = v.x; T[(p4 + 1) * 60 + lp] = v.y;
      T[(p4 + 2) * 60 + lp] = v.z; T[(p4 + 3) * 60 + lp] = v.w;
    }
    if (tid < 50) wcs[tid] = Wc[e * 2 * KC + tid];
    __syncthreads();
    int m = tid & 31, pg = tid >> 5;
#pragma unroll
    for (int j = 0; j < 2; ++j)
      for (int k2 = 0; k2 < 12; ++k2) {
        int p = pg * 12 + k2;
        float acc = 0.f;
#pragma unroll
        for (int k = 0; k < KC; ++k)
          acc = fmaf(wcs[j * 25 + k], T[p * 60 + m - k + 24], acc);
        weff[(((e * 2 + j) * P_ + p) << 9) + mc * 32 + m] = __float2bfloat16(acc);
      }
  } else {
    int e = bid - 192;
    if (bid == 192) cnt[tid] = 0;
    if (tid < 192) {
      int p = tid % 96, lg = tid / 96;
      float s = 0.f;
      const float* wp = Wp + e * D_ * P_ + p;
      for (int l = lg * 256; l < lg * 256 + 256; ++l) s += wp[l * P_];
      sm[lg * 96 + p] = s;
    }
    __syncthreads();
    if (tid < 96) s2[e * 96 + tid] = sm[tid] + sm[96 + tid];
  }
}

// logits: register-tiled LDS GEMM. Block = (b, 64-token tile, K-half).
__global__ __launch_bounds__(128) void k_logits(const float* __restrict__ x,
        const float* __restrict__ M, float* __restrict__ A0,
        float* __restrict__ A1) {
  __shared__ float xs[64 * 132];
  __shared__ float Ms[32 * 132];
  int dh = blockIdx.x & 1;
  int nt8 = (blockIdx.x >> 1) & 7;
  int b = blockIdx.x >> 4;
  int tid = threadIdx.x;
  const float* xb = x + (b * N_ + nt8 * 64) * D_ + dh * 256;
  const float* Mb = M + dh * 256;
  float acc[4][4] = {{0.f}};
  for (int kc = 0; kc < 2; ++kc) {
    for (int idx = tid; idx < 2048; idx += 128) {
      int r = idx >> 5, c4 = (idx & 31) * 4;
      *(float4*)(xs + r * 132 + c4) = *(const float4*)(xb + r * D_ + kc * 128 + c4);
    }
    for (int idx = tid; idx < 1024; idx += 128) {
      int r = idx >> 5, c4 = (idx & 31) * 4;
      *(float4*)(Ms + r * 132 + c4) = *(const float4*)(Mb + r * D_ + kc * 128 + c4);
    }
    __syncthreads();
    int nt = tid & 15, ht = tid >> 4;
#pragma unroll 4
    for (int d4 = 0; d4 < 128; d4 += 4) {
      float4 xv[4], mv[4];
#pragma unroll
      for (int i = 0; i < 4; ++i)
        xv[i] = *(const float4*)(xs + (nt + 16 * i) * 132 + d4);
#pragma unroll
      for (int j = 0; j < 4; ++j)
        mv[j] = *(const float4*)(Ms + (ht + 8 * j) * 132 + d4);
#pragma unroll
      for (int i = 0; i < 4; ++i)
#pragma unroll
        for (int j = 0; j < 4; ++j) {
          float s = acc[i][j];
          s = fmaf(xv[i].x, mv[j].x, s);
          s = fmaf(xv[i].y, mv[j].y, s);
          s = fmaf(xv[i].z, mv[j].z, s);
          s = fmaf(xv[i].w, mv[j].w, s);
          acc[i][j] = s;
        }
    }
    __syncthreads();
  }
  int nt = tid & 15, ht = tid >> 4;
  float* Ad = dh ? A1 : A0;
#pragma unroll
  for (int j = 0; j < 4; ++j) {
    int he = ht + 8 * j;
#pragma unroll
    for (int i = 0; i < 4; ++i)
      Ad[(b * HE + he) * N_ + nt8 * 64 + nt + 16 * i] = acc[i][j];
  }
}

// fused softmax + u-partials: block (nq, b), 512 threads.
// Phase A: per-he softmax stats in REGISTERS (16 lanes/he hold v[32] each,
// shuffle-reduce max & sum-exp) — A0/A1 reads are L2-hot (8 blocks share rows).
// Phase B: stage own 64-n slice normalized into As (8.4 KB LDS).
// Phase C: identical u-GEMM to k_u2.
__global__ __launch_bounds__(512) void k_u3(const float* __restrict__ x,
        const float* __restrict__ A0, const float* __restrict__ A1,
        const float* __restrict__ c, float* __restrict__ up) {
  __shared__ float As[64 * 33];
  __shared__ float mS[32], sS[32];
  int nq = blockIdx.x, b = blockIdx.y;
  int tid = threadIdx.x;
  const float scale = 0.08838834764831845f;
  {
    int wv = tid >> 6, lane = tid & 63;
    int he = wv * 4 + (lane >> 4);
    int l16 = lane & 15;
    const float* r0 = A0 + (b * HE + he) * N_;
    const float* r1 = A1 + (b * HE + he) * N_;
    float cc = c[he];
    float v[32];
    float m = -1e30f;
#pragma unroll
    for (int k = 0; k < 32; ++k) {
      int n = l16 + k * 16;
      float vv = scale * (r0[n] + r1[n] + cc);
      v[k] = vv;
      m = fmaxf(m, vv);
    }
    m = fmaxf(m, __shfl_xor(m, 1)); m = fmaxf(m, __shfl_xor(m, 2));
    m = fmaxf(m, __shfl_xor(m, 4)); m = fmaxf(m, __shfl_xor(m, 8));
    float s = 0.f;
#pragma unroll
    for (int k = 0; k < 32; ++k) s += expf(v[k] - m);
    s += __shfl_xor(s, 1); s += __shfl_xor(s, 2);
    s += __shfl_xor(s, 4); s += __shfl_xor(s, 8);
    if (l16 == 0) { mS[he] = m; sS[he] = 1.0f / s; }
  }
  __syncthreads();
  for (int idx = tid; idx < 64 * 32; idx += 512) {
    int n = idx & 63, he = idx >> 6;
    int gn = nq * 64 + n;
    float vv = scale * (A0[(b * HE + he) * N_ + gn] + A1[(b * HE + he) * N_ + gn]
                        + c[he]);
    As[n * 33 + he] = expf(vv - mS[he]) * sS[he];
  }
  __syncthreads();
  int dq = tid & 127, hg = tid >> 7;
  const float* xb = x + (b * N_ + nq * 64) * D_ + dq * 4;
  float acc[8][4];
#pragma unroll
  for (int j = 0; j < 8; ++j)
#pragma unroll
    for (int k = 0; k < 4; ++k) acc[j][k] = 0.f;
  for (int n = 0; n < 64; ++n) {
    float4 xv = *(const float4*)(xb + n * D_);
    const float* ar = As + n * 33 + hg * 8;
#pragma unroll
    for (int j = 0; j < 8; ++j) {
      float a = ar[j];
      acc[j][0] = fmaf(a, xv.x, acc[j][0]);
      acc[j][1] = fmaf(a, xv.y, acc[j][1]);
      acc[j][2] = fmaf(a, xv.z, acc[j][2]);
      acc[j][3] = fmaf(a, xv.w, acc[j][3]);
    }
  }
  float* o = up + (((b * 8 + nq) * HE) + hg * 8) * D_ + dq * 4;
#pragma unroll
  for (int j = 0; j < 8; ++j) {
    float4 v; v.x = acc[j][0]; v.y = acc[j][1]; v.z = acc[j][2]; v.w = acc[j][3];
    *(float4*)(o + j * D_) = v;
  }
}

// fused V+O projection v3, job = (b,e). 256 blocks x 512 thr.
__global__ __launch_bounds__(512) void k_vo3(const float* __restrict__ up,
        const float* __restrict__ Wv, const float* __restrict__ bv,
        const float* __restrict__ Wo, const float* __restrict__ bo,
        float* __restrict__ att) {
  __shared__ float us[4 * 512];
  __shared__ float part[4 * 512];
  __shared__ float ap_s[512];
  int b = blockIdx.x >> 3, e = blockIdx.x & 7;
  int tid = threadIdx.x;
  for (int idx = tid; idx < 4 * 128; idx += 512) {
    int h = idx >> 7, d4 = (idx & 127) * 4;
    const float* base = up + ((b * 8) * HE + h * 8 + e) * D_ + d4;
    float4 s = {0.f, 0.f, 0.f, 0.f};
#pragma unroll
    for (int nq = 0; nq < 8; ++nq) {
      float4 v = *(const float4*)(base + nq * HE * D_);
      s.x += v.x; s.y += v.y; s.z += v.z; s.w += v.w;
    }
    *(float4*)(us + h * 512 + d4) = s;
  }
  __syncthreads();
  {
    int cch = tid >> 7, j = tid & 127;
    int i0 = j * 4;
    int h = j >> 5;
    const float* ur = us + h * 512;
    const float* wv = Wv + i0;
    float4 acc = {0.f, 0.f, 0.f, 0.f};
    int d0 = cch * 128;
#pragma unroll 4
    for (int d = d0; d < d0 + 128; ++d) {
      float4 wq = *(const float4*)(wv + d * D_);
      float a = ur[d];
      acc.x = fmaf(a, wq.x, acc.x);
      acc.y = fmaf(a, wq.y, acc.y);
      acc.z = fmaf(a, wq.z, acc.z);
      acc.w = fmaf(a, wq.w, acc.w);
    }
    *(float4*)(part + cch * 512 + i0) = acc;
  }
  __syncthreads();
  ap_s[tid] = part[tid] + part[512 + tid] + part[1024 + tid] + part[1536 + tid]
              + bv[tid];
  __syncthreads();
  {
    int cch = tid >> 7, j = tid & 127;
    int o0 = j * 4;
    const float* wo = Wo + o0;
    float4 acc = {0.f, 0.f, 0.f, 0.f};
    int i0 = cch * 128;
#pragma unroll 4
    for (int i = i0; i < i0 + 128; ++i) {
      float4 wq = *(const float4*)(wo + i * D_);
      float a = ap_s[i];
      acc.x = fmaf(a, wq.x, acc.x);
      acc.y = fmaf(a, wq.y, acc.y);
      acc.z = fmaf(a, wq.z, acc.z);
      acc.w = fmaf(a, wq.w, acc.w);
    }
    *(float4*)(part + cch * 512 + o0) = acc;
  }
  __syncthreads();
  att[(b * E_ + e) * D_ + tid] = part[tid] + part[512 + tid] + part[1024 + tid]
                                 + part[1536 + tid] + bo[tid];
}

// routing (one wave per token) + fused zc
__global__ __launch_bounds__(256) void k_route2(const float* __restrict__ x,
        const float* __restrict__ att, const __hip_bfloat16* __restrict__ weff,
        const float* __restrict__ s2, const float* __restrict__ bc,
        const float* __restrict__ bp, int* __restrict__ cnt,
        int* __restrict__ tok, float* __restrict__ zc) {
  __shared__ float att_s[8 * D_];
  __shared__ float rn[8];
  __shared__ float red[4][520];
  __shared__ int blist[8][32];
  __shared__ int bcnt[8];
  int b = blockIdx.x >> 4, tile = blockIdx.x & 15;
  for (int idx = threadIdx.x; idx < 1024; idx += 256)
    *(float4*)(att_s + idx * 4) = *(const float4*)(att + b * E_ * D_ + idx * 4);
  if (threadIdx.x < 8) bcnt[threadIdx.x] = 0;
  __syncthreads();
  {
    int e = threadIdx.x >> 5, l = threadIdx.x & 31;
    float s = 0.f;
    for (int d0 = l; d0 < D_; d0 += 32) {
      float v = att_s[e * D_ + d0];
      s = fmaf(v, v, s);
    }
#pragma unroll
    for (int off = 16; off; off >>= 1) s += __shfl_xor(s, off);
    if (l == 0) rn[e] = 1.0f / sqrtf(s);
  }
  __syncthreads();
  int w = threadIdx.x >> 6, lane = threadIdx.x & 63;
  int e2 = lane & 7, ch = lane >> 3;
  float* rw = red[w];
  for (int i = 0; i < 8; ++i) {
    int t = b * N_ + tile * 32 + w * 8 + i;
    const float* xp = x + t * D_ + lane * 8;
    float4 xa = *(const float4*)xp;
    float4 xb4 = *(const float4*)(xp + 4);
    float p[8];
#pragma unroll
    for (int e = 0; e < 8; ++e) {
      const float* apt = att_s + e * D_ + lane * 8;
      float4 a0 = *(const float4*)apt;
      float4 a1 = *(const float4*)(apt + 4);
      float s = a0.x * xa.x;
      s = fmaf(a0.y, xa.y, s); s = fmaf(a0.z, xa.z, s); s = fmaf(a0.w, xa.w, s);
      s = fmaf(a1.x, xb4.x, s); s = fmaf(a1.y, xb4.y, s);
      s = fmaf(a1.z, xb4.z, s); s = fmaf(a1.w, xb4.w, s);
      p[e] = s;
    }
#pragma unroll
    for (int e = 0; e < 8; ++e) rw[e * 65 + lane] = p[e];
    float s = 0.f;
#pragma unroll
    for (int k = 0; k < 8; ++k) s += rw[e2 * 65 + ch * 8 + k];
    s += __shfl_xor(s, 8); s += __shfl_xor(s, 16); s += __shfl_xor(s, 32);
    float sc = s * rn[e2];
    int be = e2;
#pragma unroll
    for (int off = 1; off < 8; off <<= 1) {
      float o = __shfl_xor(sc, off);
      int oe = __shfl_xor(be, off);
      if (o > sc || (o == sc && oe < be)) { sc = o; be = oe; }
    }
    if (lane == 0) {
      int slot = atomicAdd(&bcnt[be], 1);
      blist[be][slot] = t;
    }
  }
  __syncthreads();
  {
    int e = threadIdx.x >> 5, r = threadIdx.x & 31;
    int ce = bcnt[e];
    int gs = 0;
    if (r == 0 && ce > 0) gs = atomicAdd(&cnt[e * 32], ce);
    gs = __shfl(gs, (threadIdx.x & 63) & 32);
    for (int k2 = r; k2 < ce; k2 += 32) tok[e * BN + gs + k2] = blist[e][k2];
  }
  int grp = threadIdx.x >> 4, l16 = threadIdx.x & 15;
  for (int r = 0; r < 3; ++r) {
    int P = tile * 48 + r * 16 + grp;
    int ez = P / 96, p = P - ez * 96;
    const short* wrow = (const short*)weff + (((ez * 2 + 1) * P_ + p) << 9);
    const float* arow = att_s + ez * D_;
    float acc = 0.f;
#pragma unroll
    for (int seg = 0; seg < 4; ++seg) {
      int d = seg * 128 + l16 * 8;
      short8 w8 = *(const short8*)(wrow + d);
      const float* a8 = arow + d;
      acc = fmaf(a8[0], b2f(w8[0]), acc); acc = fmaf(a8[1], b2f(w8[1]), acc);
      acc = fmaf(a8[2], b2f(w8[2]), acc); acc = fmaf(a8[3], b2f(w8[3]), acc);
      acc = fmaf(a8[4], b2f(w8[4]), acc); acc = fmaf(a8[5], b2f(w8[5]), acc);
      acc = fmaf(a8[6], b2f(w8[6]), acc); acc = fmaf(a8[7], b2f(w8[7]), acc);
    }
    acc += __shfl_xor(acc, 1); acc += __shfl_xor(acc, 2);
    acc += __shfl_xor(acc, 4); acc += __shfl_xor(acc, 8);
    if (l16 == 0)
      zc[(b * E_ + ez) * P_ + p] = acc + bc[ez] * s2[ez * 96 + p] + bp[ez * 96 + p];
  }
}

// grouped final GEMM: exactly-sized segmented grid, 256 threads (4 waves),
// 32 tokens x 96 cols per block.
__global__ __launch_bounds__(256) void k_final(const float* __restrict__ x,
        const __hip_bfloat16* __restrict__ weff, const float* __restrict__ zc,
        const int* __restrict__ cnt, const int* __restrict__ tok,
        float* __restrict__ out) {
  __shared__ __align__(16) unsigned short xsb[32 * 520];
  __shared__ int toks[32];
  int g = blockIdx.x;
  int cl_e[E_], bs[E_ + 1];
  bs[0] = 0;
#pragma unroll
  for (int e = 0; e < E_; ++e) {
    cl_e[e] = cnt[e * 32];
    bs[e + 1] = bs[e] + ((cl_e[e] + 31) >> 5);
  }
  if (g >= bs[E_]) return;
  int e = 0;
#pragma unroll
  for (int k = 1; k < E_; ++k) if (g >= bs[k]) e = k;
  int base = (g - bs[e]) * 32;
  int cnt_e = cl_e[e];
  int cl = cnt_e - base; if (cl > 32) cl = 32;
  int tid = threadIdx.x;
  if (tid < 32) toks[tid] = (tid < cl) ? tok[e * BN + base + tid] : tok[e * BN + base];
  __syncthreads();
  for (int idx = tid; idx < 32 * 128; idx += 256) {
    int r = idx >> 7, c4 = (idx & 127) * 4;
    float4 v = *(const float4*)(x + toks[r] * D_ + c4);
    ushort4 u4;
    u4.x = f2b(v.x); u4.y = f2b(v.y); u4.z = f2b(v.z); u4.w = f2b(v.w);
    *(ushort4*)(xsb + r * 520 + c4) = u4;
  }
  __syncthreads();
  int wave = tid >> 6, lane = tid & 63;
  int mw = wave & 1, nw = wave >> 1;
  int m16 = lane & 15, quad = lane >> 4;
  const short* w0 = (const short*)(weff + (e * 2 + 0) * P_ * D_);
  f32x4 acc[3];
#pragma unroll
  for (int nt = 0; nt < 3; ++nt) acc[nt] = (f32x4){0.f, 0.f, 0.f, 0.f};
  const short* arow = (const short*)xsb + (mw * 16 + m16) * 520 + quad * 8;
  const short* brow = w0 + (nw * 48 + m16) * D_ + quad * 8;
  for (int kt = 0; kt < 16; ++kt) {
    int koff = kt * 32;
    short8 a = *(const short8*)(arow + koff);
#pragma unroll
    for (int nt = 0; nt < 3; ++nt) {
      short8 bf = *(const short8*)(brow + nt * 16 * D_ + koff);
      acc[nt] = __builtin_amdgcn_mfma_f32_16x16x32_bf16(a, bf, acc[nt], 0, 0, 0);
    }
  }
#pragma unroll
  for (int nt = 0; nt < 3; ++nt)
#pragma unroll
    for (int rr = 0; rr < 4; ++rr) {
      int row = mw * 16 + quad * 4 + rr;
      if (row < cl) {
        int tg = toks[row];
        int bb = tg >> 9;
        int p = nw * 48 + nt * 16 + m16;
        out[tg * P_ + p] = acc[nt][rr] + zc[(bb * E_ + e) * P_ + p];
      }
    }
}

extern "C" void kernel_launch(void* const* d_in, const int* in_sizes, int n_in,
                              void* d_out, int out_size, void* d_ws, size_t ws_size,
                              hipStream_t stream) {
  const float* x      = (const float*)d_in[0];
  const float* router = (const float*)d_in[1];
  const float* Wq     = (const float*)d_in[2];
  const float* bq     = (const float*)d_in[3];
  const float* Wk     = (const float*)d_in[4];
  const float* bk     = (const float*)d_in[5];
  const float* Wv     = (const float*)d_in[6];
  const float* bv     = (const float*)d_in[7];
  const float* Wo     = (const float*)d_in[8];
  const float* bo     = (const float*)d_in[9];
  const float* Wc     = (const float*)d_in[10];
  const float* bc     = (const float*)d_in[11];
  const float* Wp     = (const float*)d_in[12];
  const float* bp     = (const float*)d_in[13];
  float* out = (float*)d_out;
  float* w = (float*)d_ws;

  int*   cnt  = (int*)(w + OCNT);
  float* s2   = w + OS2;
  float* M    = w + OM;
  float* c    = w + OC;
  float* A0   = w + OA;
  float* A1   = w + OA1;
  float* att  = w + OATT;
  int*   tok  = (int*)(w + OTOK);
  __hip_bfloat16* weff = (__hip_bfloat16*)(w + OWEFF);
  float* zc   = w + OZC;
  float* up   = w + OUP;

  k_head<<<200, 256, 0, stream>>>(router, Wq, bq, Wk, bk, Wp, Wc, M, c, cnt, s2, weff);
  k_logits<<<512, 128, 0, stream>>>(x, M, A0, A1);
  k_u3<<<dim3(8, 32), 512, 0, stream>>>(x, A0, A1, c, up);
  k_vo3<<<256, 512, 0, stream>>>(up, Wv, bv, Wo, bo, att);
  k_route2<<<512, 256, 0, stream>>>(x, att, weff, s2, bc, bp, cnt, tok, zc);
  k_final<<<520, 256, 0, stream>>>(x, weff, zc, cnt, tok, out);
}